// Round 2
// baseline (723.655 us; speedup 1.0000x reference)
//
#include <hip/hip_runtime.h>
#include <hip/hip_bf16.h>
#include <cstddef>

#define H_   22
#define T_   1000
#define B_   64
#define NSEQ (B_ * H_)      // 1408 sequences (B*C, C==22)
#define KP   22             // conv out channels
#define TP   10             // pooled time positions
#define POOL 100
#define CSTR 488            // padded dot length (484 -> 488, 61 x uint4 of bf16)

__device__ __forceinline__ float sigm(float x) {
    return __fdividef(1.f, 1.f + __expf(-x));     // saturates correctly
}
__device__ __forceinline__ float tanhfast(float x) {
    return 1.f - __fdividef(2.f, __expf(2.f * x) + 1.f);
}
__device__ __forceinline__ void unpk8(const uint4 v, float* f) {
    f[0] = __uint_as_float(v.x << 16);
    f[1] = __uint_as_float(v.x & 0xffff0000u);
    f[2] = __uint_as_float(v.y << 16);
    f[3] = __uint_as_float(v.y & 0xffff0000u);
    f[4] = __uint_as_float(v.z << 16);
    f[5] = __uint_as_float(v.z & 0xffff0000u);
    f[6] = __uint_as_float(v.w << 16);
    f[7] = __uint_as_float(v.w & 0xffff0000u);
}

// ---------------------------------------------------------------------------
// Kernel 1: batched independent LSTMs (fp32 in, bf16 hs out).
// 1 wave / block, 2 sequences / wave: lane = (seq = lane>>5, h = lane&31),
// lanes with h>=22 idle. Each lane holds the 4 gate rows of W_hh in regs,
// c/h state in regs. h-vector exchanged through LDS; single-wave block =>
// DS pipe in-order per wave; wave_barrier() pins compiler ordering.
// hs layout: [b][t][c][h] (contiguous 484-elem dot vector per (b,t)).
// ---------------------------------------------------------------------------
__global__ __launch_bounds__(64) void lstm_k(
    const float* __restrict__ xin,   // [NSEQ][T_]
    const float* __restrict__ W_ih,  // [88]
    const float* __restrict__ W_hh,  // [88][22]
    const float* __restrict__ b_ih,  // [88]
    const float* __restrict__ b_hh,  // [88]
    __hip_bfloat16* __restrict__ hsw)// [B_][T_][22][22]
{
    __shared__ float hl[2][24];
    const int lane = threadIdx.x;
    const int half = lane >> 5;
    const int hh   = lane & 31;
    if (hh >= H_) return;
    const int seq = blockIdx.x * 2 + half;
    const int b   = seq / H_;
    const int c   = seq - b * H_;

    float Wg_[4][H_];
    float wih[4], bias[4];
    #pragma unroll
    for (int g = 0; g < 4; ++g) {
        const int row = g * H_ + hh;
        wih[g]  = W_ih[row];
        bias[g] = b_ih[row] + b_hh[row];
        #pragma unroll
        for (int j = 0; j < H_; ++j)
            Wg_[g][j] = W_hh[row * H_ + j];
    }

    hl[half][hh] = 0.f;
    float creg = 0.f;
    const float* xp = xin + (size_t)seq * T_;
    float xc = xp[0];
    __hip_bfloat16* hout = hsw + ((size_t)b * T_ * (H_ * H_)) + c * H_ + hh;

    for (int t = 0; t < T_; ++t) {
        const float xn = (t + 1 < T_) ? xp[t + 1] : 0.f;
        __builtin_amdgcn_wave_barrier();
        float hj[H_];
        #pragma unroll
        for (int j = 0; j < H_; ++j) hj[j] = hl[half][j];   // prev-step h
        __builtin_amdgcn_wave_barrier();

        float a0 = fmaf(xc, wih[0], bias[0]);
        float a1 = fmaf(xc, wih[1], bias[1]);
        float a2 = fmaf(xc, wih[2], bias[2]);
        float a3 = fmaf(xc, wih[3], bias[3]);
        #pragma unroll
        for (int j = 0; j < H_; ++j) {
            a0 = fmaf(Wg_[0][j], hj[j], a0);
            a1 = fmaf(Wg_[1][j], hj[j], a1);
            a2 = fmaf(Wg_[2][j], hj[j], a2);
            a3 = fmaf(Wg_[3][j], hj[j], a3);
        }
        const float ig = sigm(a0);
        const float fg = sigm(a1);
        const float gg = tanhfast(a2);
        const float og = sigm(a3);
        creg = fmaf(fg, creg, ig * gg);
        const float hnew = og * tanhfast(creg);
        hl[half][hh] = hnew;          // ordered after this iteration's reads
        __builtin_amdgcn_wave_barrier();
        hout[0] = __float2bfloat16(hnew);
        hout += H_ * H_;
        xc = xn;
    }
}

// ---------------------------------------------------------------------------
// Kernel 2: conv(22ch, kh=22) + bias + ELU + BN(eval) + AvgPool(100).
// One block per (b, pool window p). hs tile (phased: 40/40/20 t) in LDS
// (bf16, padded stride 488 = 61 uint4/row); conv_w transposed + converted
// to bf16 in LDS. Register tile: 4 t x 2 k per thread (110/128 active).
// ---------------------------------------------------------------------------
__global__ __launch_bounds__(128) void conv_k(
    const __hip_bfloat16* __restrict__ hsw,  // [B_][T_][22][22]
    const float* __restrict__ conv_w,        // [22][22][22]
    const float* __restrict__ conv_b,        // [22]
    const float* __restrict__ bn_g,
    const float* __restrict__ bn_b,
    const float* __restrict__ bn_m,
    const float* __restrict__ bn_v,
    float* __restrict__ pooled)              // [B_][22][10]
{
    __shared__ __align__(16) __hip_bfloat16 wl[22 * CSTR];
    __shared__ __align__(16) __hip_bfloat16 hl[40 * CSTR];
    __shared__ float pp[22 * TP];

    const int tid = threadIdx.x;
    const int b = blockIdx.x / TP;
    const int p = blockIdx.x - b * TP;

    // stage conv_w transposed: wl[k][r*22+i] = conv_w[k][i][r]
    for (int d = tid; d < 22 * 484; d += 128) {
        const int k = d / 484, rem = d - k * 484;
        const int r = rem / 22, i2 = rem - r * 22;
        wl[k * CSTR + rem] = __float2bfloat16(conv_w[(k * 22 + i2) * 22 + r]);
    }
    for (int d = tid; d < 22; d += 128)
        *reinterpret_cast<uint2*>(&wl[d * CSTR + 484]) = make_uint2(0u, 0u);

    const int k2 = tid % 11;          // k pair index
    const int t4 = tid / 11;          // 4-row tile index (0..9 valid)
    const bool act = (tid < 110);
    const int k0 = 2 * k2, k1 = 2 * k2 + 1;

    float cb[2], mn[2], bt[2], inv[2];
    #pragma unroll
    for (int j = 0; j < 2; ++j) {
        const int k = k0 + j;
        cb[j] = conv_b[k];
        mn[j] = bn_m[k];
        bt[j] = bn_b[k];
        inv[j] = bn_g[k] * __frsqrt_rn(bn_v[k] + 1e-5f);
    }

    float poolsum[2] = {0.f, 0.f};
    const __hip_bfloat16* src = hsw + ((size_t)b * T_ + (size_t)p * POOL) * 484;
    const uint4* wl4 = reinterpret_cast<const uint4*>(wl);

    for (int ph = 0; ph < 3; ++ph) {
        const int rows = (ph == 2) ? 20 : 40;
        const uint2* gsrc = reinterpret_cast<const uint2*>(src + (size_t)(ph * 40) * 484);
        const int n2 = rows * 121;
        for (int idx = tid; idx < n2; idx += 128) {
            const int tr = idx / 121, col = idx - tr * 121;
            reinterpret_cast<uint2*>(&hl[tr * CSTR])[col] = gsrc[idx];
        }
        for (int idx = tid; idx < rows; idx += 128)
            *reinterpret_cast<uint2*>(&hl[idx * CSTR + 484]) = make_uint2(0u, 0u);
        __syncthreads();

        if (act && t4 < ((ph == 2) ? 5 : 10)) {
            float acc[4][2];
            #pragma unroll
            for (int i = 0; i < 4; ++i) { acc[i][0] = 0.f; acc[i][1] = 0.f; }
            const uint4* hl4 = reinterpret_cast<const uint4*>(hl);
            const int r0 = t4 * 4;
            const int w0 = k0 * 61, w1 = k1 * 61;
            for (int cch = 0; cch < 61; ++cch) {
                float wf[8], wg[8];
                unpk8(wl4[w0 + cch], wf);
                unpk8(wl4[w1 + cch], wg);
                #pragma unroll
                for (int i = 0; i < 4; ++i) {
                    float hf[8];
                    unpk8(hl4[(r0 + i) * 61 + cch], hf);
                    #pragma unroll
                    for (int e = 0; e < 8; ++e) {
                        acc[i][0] = fmaf(hf[e], wf[e], acc[i][0]);
                        acc[i][1] = fmaf(hf[e], wg[e], acc[i][1]);
                    }
                }
            }
            #pragma unroll
            for (int i = 0; i < 4; ++i) {
                #pragma unroll
                for (int j = 0; j < 2; ++j) {
                    const float s = acc[i][j] + cb[j];
                    const float e = (s > 0.f) ? s : (__expf(s) - 1.f);
                    poolsum[j] += fmaf(e - mn[j], inv[j], bt[j]);
                }
            }
        }
        __syncthreads();
    }

    if (act) {
        pp[k0 * TP + t4] = poolsum[0];
        pp[k1 * TP + t4] = poolsum[1];
    }
    __syncthreads();
    if (tid < 22) {
        float s = 0.f;
        #pragma unroll
        for (int q = 0; q < TP; ++q) s += pp[tid * TP + q];
        pooled[((size_t)b * 22 + tid) * TP + p] = s * 0.01f;
    }
}

// ---------------------------------------------------------------------------
// Kernel 3: FC [64,220] x [220,4]^T + bias -> fp32 out. One thread per output.
// ---------------------------------------------------------------------------
__global__ __launch_bounds__(256) void fc_k(
    const float* __restrict__ pooled,  // [64][220] (idx = k*10+p)
    const float* __restrict__ fc_w,    // [4][220]
    const float* __restrict__ fc_b,    // [4]
    float* __restrict__ out)           // [64][4]
{
    const int tid = threadIdx.x;
    const int b = tid >> 2, n = tid & 3;
    const float* pv = pooled + b * 220;
    const float* wv = fc_w + n * 220;
    float s = fc_b[n];
    #pragma unroll 4
    for (int j = 0; j < 220; ++j)
        s = fmaf(pv[j], wv[j], s);
    out[tid] = s;
}

extern "C" void kernel_launch(void* const* d_in, const int* in_sizes, int n_in,
                              void* d_out, int out_size, void* d_ws, size_t ws_size,
                              hipStream_t stream) {
    const float* xin    = (const float*)d_in[0];
    const float* W_ih   = (const float*)d_in[1];
    const float* W_hh   = (const float*)d_in[2];
    const float* b_ih   = (const float*)d_in[3];
    const float* b_hh   = (const float*)d_in[4];
    const float* conv_w = (const float*)d_in[5];
    const float* conv_b = (const float*)d_in[6];
    const float* bn_g   = (const float*)d_in[7];
    const float* bn_b   = (const float*)d_in[8];
    const float* bn_m   = (const float*)d_in[9];
    const float* bn_v   = (const float*)d_in[10];
    const float* fc_w   = (const float*)d_in[11];
    const float* fc_b   = (const float*)d_in[12];

    __hip_bfloat16* hsw = (__hip_bfloat16*)d_ws;                        // 61,952,000 B
    float* pooled = (float*)((char*)d_ws + (size_t)B_ * T_ * 484 * 2);  // 56,320 B

    lstm_k<<<NSEQ / 2, 64, 0, stream>>>(xin, W_ih, W_hh, b_ih, b_hh, hsw);
    conv_k<<<B_ * TP, 128, 0, stream>>>(hsw, conv_w, conv_b, bn_g, bn_b, bn_m, bn_v, pooled);
    fc_k<<<1, 256, 0, stream>>>(pooled, fc_w, fc_b, (float*)d_out);
}